// Round 6
// baseline (305.012 us; speedup 1.0000x reference)
//
#include <hip/hip_runtime.h>
#include <hip/hip_bf16.h>
#include <math.h>
#include <type_traits>

#define Bz 8
#define Tz 1024
#define Cz 1024
#define Hz 16
#define HDz 64
#define Mz (Bz*Tz)        // 8192 tokens
#define N1 (3*Cz)         // 3072 qkv width
#define QKN 2048          // Q+K buffer row stride

typedef __attribute__((ext_vector_type(8))) short short8;
typedef __attribute__((ext_vector_type(4))) short short4v;
typedef __attribute__((ext_vector_type(4))) float floatx4;

template<int V> using IC = std::integral_constant<int, V>;

__device__ __forceinline__ unsigned short f2bf(float f) {
    unsigned u = __float_as_uint(f);
    return (unsigned short)((u + 0x7FFFu + ((u >> 16) & 1u)) >> 16);
}

// pack two f32 -> bf16x2 dword (RNE; v_cvt_pk_bf16_f32 on gfx950)
__device__ __forceinline__ unsigned pkbf(float a, float b) {
    __hip_bfloat162 h = __float22bfloat162_rn(make_float2(a, b));
    return *(unsigned*)&h;
}

// async global->LDS, 16 B per lane, dest = uniform base + lane*16
__device__ __forceinline__ void gload16(const void* g, void* l) {
    __builtin_amdgcn_global_load_lds(
        (const __attribute__((address_space(1))) unsigned int*)g,
        (__attribute__((address_space(3))) unsigned int*)l, 16, 0, 0);
}

// two 16-B global loads (k-slice pair, +0 / +64 B) straight to VGPRs via asm:
// keeps the compiler's waitcnt pass out of the K-loop; sync is hand-counted.
__device__ __forceinline__ void gloadB2(const unsigned short* p, short8& d0, short8& d1) {
    asm volatile("global_load_dwordx4 %0, %2, off\n\t"
                 "global_load_dwordx4 %1, %2, off offset:64"
                 : "=&v"(d0), "=&v"(d1) : "v"(p));
}

// ---------------------------------------------------------------------------
// Merged prep: x fp32->bf16  +  Wqkv / Wproj transpose+convert.
// blockIdx.x ranges:  [0,8192) cvt   [8192,11264) Wqkv   [11264,12288) Wproj
// ---------------------------------------------------------------------------
__global__ __launch_bounds__(256) void prep_kernel(
    const float* __restrict__ x, unsigned short* __restrict__ xb,
    const float* __restrict__ Wqkv, unsigned short* __restrict__ Wqkvt,
    const float* __restrict__ Wproj, unsigned short* __restrict__ Wprojt)
{
    __shared__ float tile[32][33];
    const int bid = blockIdx.x;
    const int tid = threadIdx.x;
    if (bid < 8192) {
        int i = bid * 256 + tid;                  // 4 elems each
        float4 v = *(const float4*)&x[(size_t)i * 4];
        ushort4 o;
        o.x = f2bf(v.x); o.y = f2bf(v.y); o.z = f2bf(v.z); o.w = f2bf(v.w);
        *(ushort4*)&xb[(size_t)i * 4] = o;
        return;
    }
    const float* W; unsigned short* Wt; int K, N, n0, k0;
    if (bid < 11264) {
        int b = bid - 8192;  W = Wqkv;  Wt = Wqkvt;  K = Cz; N = N1;
        n0 = (b % 96) * 32;  k0 = (b / 96) * 32;
    } else {
        int b = bid - 11264; W = Wproj; Wt = Wprojt; K = Cz; N = Cz;
        n0 = (b % 32) * 32;  k0 = (b / 32) * 32;
    }
    const int tx = tid & 31, ty = tid >> 5;       // (32,8)
#pragma unroll
    for (int i = 0; i < 4; ++i)
        tile[ty + i * 8][tx] = W[(size_t)(k0 + ty + i * 8) * N + n0 + tx];
    __syncthreads();
#pragma unroll
    for (int i = 0; i < 4; ++i)
        Wt[(size_t)(n0 + ty + i * 8) * K + k0 + tx] = f2bf(tile[tx][ty + i * 8]);
}

// ---------------------------------------------------------------------------
// QKV GEMM v6: 128x192 tile, B DIRECT TO REGISTERS (no LDS round trip).
// R5 PMC model: LDS pipe ~73% busy (14 b128 reads + 5 staged units per
// wave-tile) vs MFMA 34% -> LDS-throughput-bound.  B's fragment pattern is a
// plain per-lane global address (swizzles cancel: LDS[r][c] held global chunk
// c^(r&7), read back at chunk^(r&7) -> identity), so B loads go straight to
// VGPRs via asm global_load_dwordx4, double-buffered bE/bO (static ping-pong,
// issued for kt+2 right after last use).  LDS holds A only: 32 KiB/block,
// reads/wave-tile 14 -> 8, MFMA:ds ratio 1.71 -> 3.0.
// vmcnt audit (steady state, end of tile kt): queue = [bfr(kt+1) 6 | A(kt+1)
// 2 | bfr(kt+2) 6] -> vmcnt(6) proves tile kt+1's data landed; kt==14 ->
// vmcnt(0); kt==15 -> nothing outstanding.  One barrier per tile.
// XCD map: xcd covers 2 bx x 64 by (by-inner) -> B slice 768 KB stays
// L2-resident; A panels shared by the bx pair back-to-back.
// ---------------------------------------------------------------------------
__global__ __launch_bounds__(512, 4) void gemm128_qkv(
    const unsigned short* __restrict__ A,
    const unsigned short* __restrict__ Bt,
    const float* __restrict__ bias,
    unsigned short* __restrict__ Cqk, unsigned short* __restrict__ VtG)
{
    __shared__ unsigned short lds[2 * 8192];    // [buf][A 128x64]
    constexpr int NT = 16;                       // K / 64

    const int tid = threadIdx.x;
    const int lane = tid & 63;
    const int w = tid >> 6;                 // 0..7
    const int wm = w >> 2, wn = w & 3;      // 2M x 4N wave grid
    const int quad = lane >> 4, m16 = lane & 15;
    const int sw7 = m16 & 7;

    // XCD map: xcd = bid&7 owns bx in {2*xcd, 2*xcd+1}, by-inner pairs
    const int bid = blockIdx.x;
    const int xcd = bid & 7, c = bid >> 3;       // c in [0,128)
    const int by = c >> 1, bx = xcd * 2 + (c & 1);
    const int row0 = by * 128, col0 = bx * 192;

    // A staging source: row srow of the 64-row unit, pre-swizzled col chunk
    const int srow = tid >> 3;                              // 0..63
    const int scol = ((tid & 7) ^ (srow & 7)) * 8;
    const unsigned short* a0 = A + (size_t)(row0 + srow) * Cz + scol;

    auto stageA = [&](int kt, int db) {
        unsigned short* d = &lds[db * 8192 + w * 512];
        gload16(a0 + kt * 64, d);
        gload16(a0 + kt * 64 + 64 * Cz, d + 4096);
    };

    // B per-lane base: row = col0 + wn*48 + ni*16 + m16, k-chunk quad*8
    const unsigned short* pB = Bt + (size_t)(col0 + wn * 48 + m16) * Cz + quad * 8;

    floatx4 acc[4][3];
#pragma unroll
    for (int mi = 0; mi < 4; ++mi)
#pragma unroll
        for (int ni = 0; ni < 3; ++ni)
            acc[mi][ni] = (floatx4){0.f, 0.f, 0.f, 0.f};

    short8 bE[3][2], bO[3][2];

    // prologue: A(0)->buf0; B(0)->bE; B(1)->bO
    stageA(0, 0);
#pragma unroll
    for (int ni = 0; ni < 3; ++ni)
        gloadB2(pB + ni * 16 * Cz, bE[ni][0], bE[ni][1]);
#pragma unroll
    for (int ni = 0; ni < 3; ++ni)
        gloadB2(pB + ni * 16 * Cz + 64, bO[ni][0], bO[ni][1]);
    asm volatile("s_waitcnt vmcnt(6)" ::: "memory");   // A(0)+bE landed
    asm volatile("s_barrier" ::: "memory");

    auto body = [&](const int kt, short8 (&bfr)[3][2]) {
        const int b = kt & 1;
        const unsigned short* lA = &lds[b * 8192];

        // phase 0: af(mi 0,1); stage A(kt+1) -> buf^1
        short8 af[2][2];
#pragma unroll
        for (int jj = 0; jj < 2; ++jj)
#pragma unroll
            for (int ks = 0; ks < 2; ++ks)
                af[jj][ks] = *(const short8*)&lA[wm * 4096 + (jj * 16 + m16) * 64
                                                 + ((((ks << 2) | quad) ^ sw7) << 3)];
        if (kt + 1 < NT) stageA(kt + 1, b ^ 1);
        asm volatile("s_waitcnt lgkmcnt(0)" ::: "memory");
        __builtin_amdgcn_sched_barrier(0);
        __builtin_amdgcn_s_setprio(1);
#pragma unroll
        for (int ks = 0; ks < 2; ++ks)
#pragma unroll
            for (int jj = 0; jj < 2; ++jj)
#pragma unroll
                for (int ni = 0; ni < 3; ++ni)
                    acc[jj][ni] = __builtin_amdgcn_mfma_f32_16x16x32_bf16(
                        af[jj][ks], bfr[ni][ks], acc[jj][ni], 0, 0, 0);
        __builtin_amdgcn_s_setprio(0);

        // phase 1: af(mi 2,3), same registers (dead after MFMA01)
#pragma unroll
        for (int jj = 0; jj < 2; ++jj)
#pragma unroll
            for (int ks = 0; ks < 2; ++ks)
                af[jj][ks] = *(const short8*)&lA[wm * 4096 + ((2 + jj) * 16 + m16) * 64
                                                 + ((((ks << 2) | quad) ^ sw7) << 3)];
        asm volatile("s_waitcnt lgkmcnt(0)" ::: "memory");
        __builtin_amdgcn_sched_barrier(0);
        __builtin_amdgcn_s_setprio(1);
#pragma unroll
        for (int ks = 0; ks < 2; ++ks)
#pragma unroll
            for (int jj = 0; jj < 2; ++jj)
#pragma unroll
                for (int ni = 0; ni < 3; ++ni)
                    acc[2 + jj][ni] = __builtin_amdgcn_mfma_f32_16x16x32_bf16(
                        af[jj][ks], bfr[ni][ks], acc[2 + jj][ni], 0, 0, 0);
        __builtin_amdgcn_s_setprio(0);

        // reload this frag set for kt+2 (regs dead now; WAR keeps order)
        if (kt + 2 < NT) {
#pragma unroll
            for (int ni = 0; ni < 3; ++ni)
                gloadB2(pB + ni * 16 * Cz + (kt + 2) * 64, bfr[ni][0], bfr[ni][1]);
        }
        if (kt <= NT - 3)      { asm volatile("s_waitcnt vmcnt(6)" ::: "memory"); }
        else if (kt == NT - 2) { asm volatile("s_waitcnt vmcnt(0)" ::: "memory"); }
        if (kt < NT - 1) { asm volatile("s_barrier" ::: "memory"); }
    };

#pragma unroll 1
    for (int k2 = 0; k2 < NT / 2; ++k2) {
        body(2 * k2,     bE);
        body(2 * k2 + 1, bO);
    }

    // -------- epilogue: per-(wave,ni) Q/K vs V branch --------
    float bv[3];
#pragma unroll
    for (int ni = 0; ni < 3; ++ni)
        bv[ni] = bias[col0 + wn * 48 + ni * 16 + m16];
#pragma unroll
    for (int ni = 0; ni < 3; ++ni) {
        const int c0 = col0 + wn * 48 + ni * 16;      // lane adds m16
        if (c0 < 2048) {
            // Q/K: bf16 rows at stride QKN
#pragma unroll
            for (int mi = 0; mi < 4; ++mi)
#pragma unroll
                for (int reg = 0; reg < 4; ++reg) {
                    const int r = row0 + wm * 64 + mi * 16 + quad * 4 + reg;
                    Cqk[(size_t)r * QKN + c0 + m16] = f2bf(acc[mi][ni][reg] + bv[ni]);
                }
        } else {
            // V: direct transposed store to VtG[bh][d][t] (8-B runs, 4 tokens)
            const int cb = c0 - 2048;
            const int hsel = cb >> 6;                 // head
            const int dd = (cb & 63) + m16;           // feature within head
            const int bq = row0 >> 10;                // batch
            const int tb = row0 & 1023;
            unsigned short* drow = VtG
                + (size_t)(bq * Hz + hsel) * (HDz * Tz)
                + (size_t)dd * Tz + tb;
#pragma unroll
            for (int mi = 0; mi < 4; ++mi) {
                const int t = wm * 64 + mi * 16 + quad * 4;
                unsigned pk[2];
                pk[0] = pkbf(acc[mi][ni][0] + bv[ni], acc[mi][ni][1] + bv[ni]);
                pk[1] = pkbf(acc[mi][ni][2] + bv[ni], acc[mi][ni][3] + bv[ni]);
                *(uint2*)&drow[t] = *(uint2*)pk;
            }
        }
    }
}

// ---------------------------------------------------------------------------
// proj GEMM template (R3-measured improvement, kept verbatim).
// 256x128 tile, intra-tile pipelined, 256 blocks = exactly 1 dispatch wave.
// ---------------------------------------------------------------------------
template<int NI, int MODE, int NXB>
__global__ __launch_bounds__(512) void gemm8p(
    const unsigned short* __restrict__ A,
    const unsigned short* __restrict__ Bt,
    const float* __restrict__ bias,
    void* __restrict__ Cout, unsigned short* __restrict__ VtG)
{
    constexpr int LDSB = 16384 + NI * 4096;   // shorts per buffer
    constexpr int NT = 16;                    // K / 64
    constexpr int NBLK = (Mz / 256) * NXB;
    constexpr int CHUNK = NBLK / 8;
    constexpr int NOUT = NXB * NI * 64;       // output row width
    __shared__ unsigned short lds[2 * LDSB];

    const int tid = threadIdx.x;
    const int lane = tid & 63;
    const int w = tid >> 6;                 // 0..7
    const int wm = w >> 2, wn = w & 3;      // 2M x 4N wave grid
    const int quad = lane >> 4, m16 = lane & 15;
    const int sw7 = m16 & 7;

    int wg = blockIdx.x;
    wg = (wg & 7) * CHUNK + (wg >> 3);
    const int bx = wg % NXB, by = wg / NXB;
    const int row0 = by * 256, col0 = bx * (NI * 64);

    const int srow = tid >> 3;                              // 0..63
    const int scol = ((tid & 7) ^ (srow & 7)) * 8;          // pre-swizzled src
    const unsigned short* sA[2][2];
    const unsigned short* sBu[NI];
#pragma unroll
    for (int h = 0; h < 2; ++h)
#pragma unroll
        for (int c = 0; c < 2; ++c)
            sA[h][c] = A + (size_t)(row0 + h * 128 + c * 64 + srow) * Cz + scol;
#pragma unroll
    for (int u = 0; u < NI; ++u)
        sBu[u] = Bt + (size_t)(col0 + u * 64 + srow) * Cz + scol;

    auto stage_tile = [&](int kt, int db) {
        unsigned short* base = &lds[db * LDSB];
#pragma unroll
        for (int u = 0; u < NI; ++u)
            gload16(sBu[u] + kt * 64, base + 16384 + u * 4096 + w * 512);
        gload16(sA[0][0] + kt * 64, base + w * 512);
        gload16(sA[0][1] + kt * 64, base + w * 512 + 4096);
        gload16(sA[1][0] + kt * 64, base + 8192 + w * 512);
        gload16(sA[1][1] + kt * 64, base + 8192 + w * 512 + 4096);
    };

    float bv[NI];
#pragma unroll
    for (int ni = 0; ni < NI; ++ni)
        bv[ni] = bias[col0 + wn * (NI * 16) + ni * 16 + m16];
    asm volatile("s_waitcnt vmcnt(0)" ::: "memory");

    floatx4 acc[8][NI];
#pragma unroll
    for (int mi = 0; mi < 8; ++mi)
#pragma unroll
        for (int ni = 0; ni < NI; ++ni)
            acc[mi][ni] = (floatx4){0.f, 0.f, 0.f, 0.f};

    stage_tile(0, 0);
    stage_tile(1, 1);

    int b = 0;
#pragma unroll 1
    for (int kt = 0; kt < NT; ++kt, b ^= 1) {
        if (kt < NT - 1) {
            if constexpr (NI == 3) asm volatile("s_waitcnt vmcnt(7)" ::: "memory");
            else                   asm volatile("s_waitcnt vmcnt(6)" ::: "memory");
        } else {
            asm volatile("s_waitcnt vmcnt(0)" ::: "memory");
        }
        asm volatile("s_barrier" ::: "memory");

        const unsigned short* lA = &lds[b * LDSB];
        const unsigned short* lB = &lds[b * LDSB + 16384];

        auto loadA = [&](auto pc, short8 (&af)[2][2]) {
            constexpr int p = decltype(pc)::value;
            constexpr int hf = p >> 1;
#pragma unroll
            for (int j = 0; j < 2; ++j) {
                const int ra = ((p & 1) * 64 + j * 32 + wm * 16 + m16) * 64;
#pragma unroll
                for (int ks = 0; ks < 2; ++ks)
                    af[j][ks] = *(const short8*)&lA[hf * 8192 + ra + ((((ks << 2) | quad) ^ sw7) << 3)];
            }
        };

        short8 bfr[NI][2];
#pragma unroll
        for (int ni = 0; ni < NI; ++ni) {
            const int rb = (wn * (NI * 16) + ni * 16 + m16) * 64;
#pragma unroll
            for (int ks = 0; ks < 2; ++ks)
                bfr[ni][ks] = *(const short8*)&lB[rb + ((((ks << 2) | quad) ^ sw7) << 3)];
        }

        auto cluster = [&](auto pc, short8 (&af)[2][2]) {
            constexpr int p = decltype(pc)::value;
            __builtin_amdgcn_s_setprio(1);
#pragma unroll
            for (int ks = 0; ks < 2; ++ks)
#pragma unroll
                for (int j = 0; j < 2; ++j)
#pragma unroll
                    for (int ni = 0; ni < NI; ++ni)
                        acc[p * 2 + j][ni] = __builtin_amdgcn_mfma_f32_16x16x32_bf16(
                            af[j][ks], bfr[ni][ks], acc[p * 2 + j][ni], 0, 0, 0);
            __builtin_amdgcn_s_setprio(0);
        };

        short8 afA[2][2], afB[2][2];
        loadA(IC<0>{}, afA);
        __builtin_amdgcn_sched_barrier(0);
        loadA(IC<1>{}, afB);
        __builtin_amdgcn_sched_barrier(0);
        asm volatile("s_waitcnt lgkmcnt(4)" ::: "memory");
        __builtin_amdgcn_sched_barrier(0);
        cluster(IC<0>{}, afA);
        loadA(IC<2>{}, afA);
        __builtin_amdgcn_sched_barrier(0);
        asm volatile("s_waitcnt lgkmcnt(4)" ::: "memory");
        __builtin_amdgcn_sched_barrier(0);
        cluster(IC<1>{}, afB);
        loadA(IC<3>{}, afB);
        __builtin_amdgcn_sched_barrier(0);
        asm volatile("s_waitcnt lgkmcnt(4)" ::: "memory");
        __builtin_amdgcn_sched_barrier(0);
        cluster(IC<2>{}, afA);
        asm volatile("s_waitcnt lgkmcnt(0)" ::: "memory");
        __builtin_amdgcn_sched_barrier(0);
        if (kt + 2 < NT) {
            asm volatile("s_barrier" ::: "memory");
            stage_tile(kt + 2, b);
        }
        __builtin_amdgcn_sched_barrier(0);
        cluster(IC<3>{}, afB);
    }

    // -------- epilogue --------
    if constexpr (MODE == 0) {
#pragma unroll
        for (int ni = 0; ni < NI; ++ni) {
            const int c = col0 + wn * (NI * 16) + ni * 16 + m16;
#pragma unroll
            for (int mi = 0; mi < 8; ++mi)
#pragma unroll
                for (int reg = 0; reg < 4; ++reg) {
                    const int r = row0 + mi * 32 + wm * 16 + quad * 4 + reg;
                    ((float*)Cout)[(size_t)r * NOUT + c] = acc[mi][ni][reg] + bv[ni];
                }
        }
    } else {
#pragma unroll
        for (int ni = 0; ni < NI; ++ni) {
            const int c0 = col0 + wn * (NI * 16) + ni * 16;
            if (c0 < 2048) {
#pragma unroll
                for (int mi = 0; mi < 8; ++mi)
#pragma unroll
                    for (int reg = 0; reg < 4; ++reg) {
                        const int r = row0 + mi * 32 + wm * 16 + quad * 4 + reg;
                        ((unsigned short*)Cout)[(size_t)r * QKN + c0 + m16] =
                            f2bf(acc[mi][ni][reg] + bv[ni]);
                    }
            } else {
                const int cb = c0 - 2048;
                const int hsel = cb >> 6;
                const int dd = (cb & 63) + m16;
                const int bq = row0 >> 10;
                const int tb = row0 & 1023;
                unsigned short* drow = VtG
                    + (size_t)(bq * Hz + hsel) * (HDz * Tz)
                    + (size_t)dd * Tz + tb;
#pragma unroll
                for (int mi = 0; mi < 8; ++mi) {
                    const int t = mi * 32 + wm * 16 + quad * 4;
                    unsigned pk[2];
                    pk[0] = pkbf(acc[mi][ni][0] + bv[ni], acc[mi][ni][1] + bv[ni]);
                    pk[1] = pkbf(acc[mi][ni][2] + bv[ni], acc[mi][ni][3] + bv[ni]);
                    *(uint2*)&drow[t] = *(uint2*)pk;
                }
            }
        }
    }
}

// ---------------------------------------------------------------------------
// MFMA causal flash attention (R5-verified 1-D grid: XCD = bh%8 -> K/V L2
// locality; body unchanged).
// ---------------------------------------------------------------------------
__global__ __launch_bounds__(128) void attn_kernel(const unsigned short* __restrict__ qkb,
    const unsigned short* __restrict__ VtG, unsigned short* __restrict__ attb)
{
    __shared__ unsigned short Ks[2][64 * 64];   // [key][d swizzled]
    __shared__ unsigned short Vs[2][64 * 64];   // [d][key swizzled]

    const int bid = blockIdx.x;
    const int bx = bid >> 7;                    // 0..7
    const int bh = bid & 127;
    const int b = bh >> 4, h = bh & 15;
    const int tid = threadIdx.x, lane = tid & 63, w = tid >> 6;   // w in {0,1}
    const int quad = lane >> 4, m16 = lane & 15;
    const int qis[2] = {15 - bx, bx};           // big tile first

    const unsigned short* Kb = qkb + (size_t)(b * Tz) * QKN + Cz + h * HDz;
    const unsigned short* Vb = VtG + (size_t)bh * (HDz * Tz);

    const int l3 = lane >> 3, l7 = lane & 7;
    const int gsw = ((l7 ^ l3) << 3);           // staging source swizzle
    const int sw = m16 & 7;                     // read-side row swizzle key
    const int p0 = (quad ^ sw) << 3;            // K-frag group offset (elems)

    // ones A-frag for the l-sum MFMA: A[m=0][k]=1, else 0
    short8 onesf = (short8){0,0,0,0,0,0,0,0};
    if (m16 == 0) {
        const short one = (short)0x3F80;
        onesf = (short8){one,one,one,one,one,one,one,one};
    }

    int srow[4];
#pragma unroll
    for (int i = 0; i < 4; ++i) srow[i] = w * 32 + i * 8 + l3;

    // prologue: stage key-tile 0 into buf 0
#pragma unroll
    for (int i = 0; i < 4; ++i) {
        gload16(Kb + (size_t)srow[i] * QKN + gsw, &Ks[0][(w * 4 + i) * 512]);
        gload16(Vb + (size_t)srow[i] * Tz + gsw, &Vs[0][(w * 4 + i) * 512]);
    }

    int buf = 0;
    for (int t = 0; t < 2; ++t) {
        const int qi = qis[t];

        // Q B-frags: rows qi*64 + w*32 + mi*16 + m16
        short8 qf[2][2];
        int qrow[2];
#pragma unroll
        for (int mi = 0; mi < 2; ++mi) {
            qrow[mi] = qi * 64 + w * 32 + mi * 16 + m16;
            const size_t rq = (size_t)(b * Tz + qrow[mi]) * QKN + h * HDz;
            qf[mi][0] = *(const short8*)&qkb[rq + quad * 8];
            qf[mi][1] = *(const short8*)&qkb[rq + 32 + quad * 8];
        }

        floatx4 of[2][4];   // O^T accum: [d=dc*16+quad*4+reg][q=m16]
#pragma unroll
        for (int mi = 0; mi < 2; ++mi)
#pragma unroll
            for (int dc = 0; dc < 4; ++dc) of[mi][dc] = (floatx4){0.f, 0.f, 0.f, 0.f};
        floatx4 lsum[2];
        lsum[0] = (floatx4){0.f, 0.f, 0.f, 0.f};
        lsum[1] = (floatx4){0.f, 0.f, 0.f, 0.f};

        auto tile_body = [&](auto diag_c) {
            constexpr bool DIAG = decltype(diag_c)::value;
            short8 pf[2][2];
#pragma unroll
            for (int m0 = 0; m0 < 4; ++m0) {
                if (DIAG && w == 0 && m0 >= 2) continue;
                const unsigned short* kr = &Ks[buf][(m0 * 16 + m16) * 64];
                short8 kf0 = *(const short8*)&kr[p0];
                short8 kf1 = *(const short8*)&kr[p0 ^ 32];
#pragma unroll
                for (int mi = 0; mi < 2; ++mi) {
                    floatx4 st = (floatx4){0.f, 0.f, 0.f, 0.f};
                    st = __builtin_amdgcn_mfma_f32_16x16x32_bf16(kf0, qf[mi][0], st, 0, 0, 0);
                    st = __builtin_amdgcn_mfma_f32_16x16x32_bf16(kf1, qf[mi][1], st, 0, 0, 0);
                    float p[4];
#pragma unroll
                    for (int reg = 0; reg < 4; ++reg) {
                        p[reg] = exp2f(st[reg] * 0.18033688f);
                        if (DIAG) {
                            int key = m0 * 16 + quad * 4 + reg;
                            int qr  = w * 32 + mi * 16 + m16;
                            p[reg] = (key <= qr) ? p[reg] : 0.f;
                        }
                    }
                    unsigned* pp = (unsigned*)&pf[mi][m0 >> 1];
                    pp[(m0 & 1) * 2 + 0] = pkbf(p[0], p[1]);
                    pp[(m0 & 1) * 2 + 1] = pkbf(p[2], p[3]);
                }
            }
#pragma unroll
            for (int kg = 0; kg < 2; ++kg) {
                if (DIAG && w == 0 && kg == 1) continue;
#pragma unroll
                for (int mi = 0; mi < 2; ++mi)
                    lsum[mi] = __builtin_amdgcn_mfma_f32_16x16x32_bf16(onesf, pf[mi][kg], lsum[mi], 0, 0, 0);
#pragma unroll
                for (int dc = 0; dc < 4; ++dc) {
                    const unsigned short* vrow = &Vs[buf][(dc * 16 + m16) * 64];
                    const int g0 = kg * 4 + (quad >> 1);
                    const int off = (quad & 1) * 4;
                    short4v v0 = *(const short4v*)&vrow[((g0 ^ sw) << 3) + off];
                    short4v v1 = *(const short4v*)&vrow[(((g0 + 2) ^ sw) << 3) + off];
                    short8 vf;
                    vf[0] = v0[0]; vf[1] = v0[1]; vf[2] = v0[2]; vf[3] = v0[3];
                    vf[4] = v1[0]; vf[5] = v1[1]; vf[6] = v1[2]; vf[7] = v1[3];
#pragma unroll
                    for (int mi = 0; mi < 2; ++mi)
                        of[mi][dc] = __builtin_amdgcn_mfma_f32_16x16x32_bf16(vf, pf[mi][kg], of[mi][dc], 0, 0, 0);
                }
            }
        };

        for (int ki = 0; ki <= qi; ++ki) {
            __syncthreads();
            const int nk = (ki < qi) ? (ki + 1) : (t == 0 ? 0 : -1);
            if (nk >= 0) {
                const size_t ko = (size_t)nk * 64;
#pragma unroll
                for (int i = 0; i < 4; ++i) {
                    gload16(Kb + (ko + srow[i]) * QKN + gsw, &Ks[buf ^ 1][(w * 4 + i) * 512]);
                    gload16(Vb + (size_t)srow[i] * Tz + ko + gsw, &Vs[buf ^ 1][(w * 4 + i) * 512]);
                }
            }
            if (ki == qi) tile_body(std::true_type{});
            else          tile_body(std::false_type{});
            buf ^= 1;
        }

#pragma unroll
        for (int mi = 0; mi < 2; ++mi) {
            const float l = __shfl(lsum[mi][0], m16);   // from lanes 0..15
            const float inv = 1.f / l;
            const size_t orow = (size_t)(b * Tz + qrow[mi]) * Cz + h * HDz;
#pragma unroll
            for (int dc = 0; dc < 4; ++dc) {
                ushort4 o;
                o.x = f2bf(of[mi][dc][0] * inv);
                o.y = f2bf(of[mi][dc][1] * inv);
                o.z = f2bf(of[mi][dc][2] * inv);
                o.w = f2bf(of[mi][dc][3] * inv);
                *(ushort4*)&attb[orow + dc * 16 + quad * 4] = o;
            }
        }
    }
}

// ---------------------------------------------------------------------------
extern "C" void kernel_launch(void* const* d_in, const int* in_sizes, int n_in,
                              void* d_out, int out_size, void* d_ws, size_t ws_size,
                              hipStream_t stream)
{
    const float* x     = (const float*)d_in[0];
    const float* Wqkv  = (const float*)d_in[1];
    const float* bqkv  = (const float*)d_in[2];
    const float* Wproj = (const float*)d_in[3];
    const float* bproj = (const float*)d_in[4];
    float* out = (float*)d_out;

    // Workspace (76 MB): attb aliases xb (xb fully consumed by gemm1 before
    // attn writes attb; stream-ordered, re-poison-safe).
    unsigned short* xb     = (unsigned short*)d_ws;              // 16 MB
    unsigned short* Wqkvt  = xb + (size_t)Mz * Cz;               //  6 MB
    unsigned short* Wprojt = Wqkvt + (size_t)N1 * Cz;            //  2 MB
    unsigned short* qkb    = Wprojt + (size_t)Cz * Cz;           // 32 MB
    unsigned short* VtG    = qkb + (size_t)Mz * QKN;             // 16 MB
    unsigned short* attb   = xb;                                 // alias

    prep_kernel<<<12288, 256, 0, stream>>>(x, xb, Wqkv, Wqkvt, Wproj, Wprojt);

    // QKV GEMM: 128x192 tile, A-only LDS (32 KiB), B direct-to-register
    gemm128_qkv<<<1024, 512, 0, stream>>>(xb, Wqkvt, bqkv, qkb, VtG);

    // attn: 1-D grid, bh in low bits -> same-bh blocks share an XCD (L2 reuse)
    attn_kernel<<<1024, 128, 0, stream>>>(qkb, VtG, attb);

    gemm8p<2, 0, 8><<<256, 512, 0, stream>>>(attb, Wprojt, bproj, out, nullptr);
}

// Round 7
// 225.107 us; speedup vs baseline: 1.3550x; 1.3550x over previous
//
#include <hip/hip_runtime.h>
#include <hip/hip_bf16.h>
#include <math.h>
#include <type_traits>

#define Bz 8
#define Tz 1024
#define Cz 1024
#define Hz 16
#define HDz 64
#define Mz (Bz*Tz)        // 8192 tokens
#define N1 (3*Cz)         // 3072 qkv width
#define QKN 2048          // Q+K buffer row stride

typedef __attribute__((ext_vector_type(8))) short short8;
typedef __attribute__((ext_vector_type(4))) short short4v;
typedef __attribute__((ext_vector_type(4))) float floatx4;

template<int V> using IC = std::integral_constant<int, V>;

__device__ __forceinline__ unsigned short f2bf(float f) {
    unsigned u = __float_as_uint(f);
    return (unsigned short)((u + 0x7FFFu + ((u >> 16) & 1u)) >> 16);
}

// pack two f32 -> bf16x2 dword (RNE; v_cvt_pk_bf16_f32 on gfx950)
__device__ __forceinline__ unsigned pkbf(float a, float b) {
    __hip_bfloat162 h = __float22bfloat162_rn(make_float2(a, b));
    return *(unsigned*)&h;
}

// async global->LDS, 16 B per lane, dest = uniform base + lane*16
__device__ __forceinline__ void gload16(const void* g, void* l) {
    __builtin_amdgcn_global_load_lds(
        (const __attribute__((address_space(1))) unsigned int*)g,
        (__attribute__((address_space(3))) unsigned int*)l, 16, 0, 0);
}

// ---------------------------------------------------------------------------
// Merged prep: x fp32->bf16  +  Wqkv / Wproj transpose+convert.
// blockIdx.x ranges:  [0,8192) cvt   [8192,11264) Wqkv   [11264,12288) Wproj
// ---------------------------------------------------------------------------
__global__ __launch_bounds__(256) void prep_kernel(
    const float* __restrict__ x, unsigned short* __restrict__ xb,
    const float* __restrict__ Wqkv, unsigned short* __restrict__ Wqkvt,
    const float* __restrict__ Wproj, unsigned short* __restrict__ Wprojt)
{
    __shared__ float tile[32][33];
    const int bid = blockIdx.x;
    const int tid = threadIdx.x;
    if (bid < 8192) {
        int i = bid * 256 + tid;                  // 4 elems each
        float4 v = *(const float4*)&x[(size_t)i * 4];
        ushort4 o;
        o.x = f2bf(v.x); o.y = f2bf(v.y); o.z = f2bf(v.z); o.w = f2bf(v.w);
        *(ushort4*)&xb[(size_t)i * 4] = o;
        return;
    }
    const float* W; unsigned short* Wt; int K, N, n0, k0;
    if (bid < 11264) {
        int b = bid - 8192;  W = Wqkv;  Wt = Wqkvt;  K = Cz; N = N1;
        n0 = (b % 96) * 32;  k0 = (b / 96) * 32;
    } else {
        int b = bid - 11264; W = Wproj; Wt = Wprojt; K = Cz; N = Cz;
        n0 = (b % 32) * 32;  k0 = (b / 32) * 32;
    }
    const int tx = tid & 31, ty = tid >> 5;       // (32,8)
#pragma unroll
    for (int i = 0; i < 4; ++i)
        tile[ty + i * 8][tx] = W[(size_t)(k0 + ty + i * 8) * N + n0 + tx];
    __syncthreads();
#pragma unroll
    for (int i = 0; i < 4; ++i)
        Wt[(size_t)(n0 + ty + i * 8) * K + k0 + tx] = f2bf(tile[tx][ty + i * 8]);
}

// ---------------------------------------------------------------------------
// QKV GEMM (R5-verified, 61 us): 128x192 tile, BK=64, LDS 80 KiB -> 2
// blocks/CU cross-block overlap.  REVERTED from R6's B-to-register variant:
// that needed ~48 extra VGPRs under the 128-cap of launch_bounds(512,4) ->
// compiler spilled B buffers to scratch (VGPR 64, WRITE_SIZE 50->126 MB,
// 148 us).  B stays in LDS: one copy shared by 8 waves.
// ---------------------------------------------------------------------------
__global__ __launch_bounds__(512, 4) void gemm128_qkv(
    const unsigned short* __restrict__ A,
    const unsigned short* __restrict__ Bt,
    const float* __restrict__ bias,
    unsigned short* __restrict__ Cqk, unsigned short* __restrict__ VtG)
{
    __shared__ unsigned short lds[2 * 20480];   // [buf][A:8192 | B:12288]
    constexpr int NT = 16;                       // K / 64

    const int tid = threadIdx.x;
    const int lane = tid & 63;
    const int w = tid >> 6;                 // 0..7
    const int wm = w >> 2, wn = w & 3;      // 2M x 4N wave grid
    const int quad = lane >> 4, m16 = lane & 15;
    const int sw7 = m16 & 7;

    // XCD-aware bijective swizzle (1024 % 8 == 0)
    int wg = blockIdx.x;
    wg = (wg & 7) * 128 + (wg >> 3);
    const int bx = wg & 15, by = wg >> 4;
    const int row0 = by * 128, col0 = bx * 192;

    // staging source: row srow of the 64-row unit, pre-swizzled col chunk
    const int srow = tid >> 3;                              // 0..63
    const int scol = ((tid & 7) ^ (srow & 7)) * 8;
    const unsigned short* a0 = A  + (size_t)(row0 + srow) * Cz + scol;
    const unsigned short* b0 = Bt + (size_t)(col0 + srow) * Cz + scol;

    auto stageA = [&](int kt, int db) {
        unsigned short* d = &lds[db * 20480 + w * 512];
        gload16(a0 + kt * 64, d);
        gload16(a0 + kt * 64 + 64 * Cz, d + 4096);
    };
    auto stageB = [&](int kt, int db) {
        unsigned short* d = &lds[db * 20480 + 8192 + w * 512];
        gload16(b0 + kt * 64, d);
        gload16(b0 + kt * 64 + 64 * Cz, d + 4096);
        gload16(b0 + kt * 64 + 128 * Cz, d + 8192);
    };

    float bv[3];
#pragma unroll
    for (int ni = 0; ni < 3; ++ni)
        bv[ni] = bias[col0 + wn * 48 + ni * 16 + m16];
    // drain bias loads so hand-counted vmcnt gating below stays exact
    asm volatile("s_waitcnt vmcnt(0)" ::: "memory");

    floatx4 acc[4][3];
#pragma unroll
    for (int mi = 0; mi < 4; ++mi)
#pragma unroll
        for (int ni = 0; ni < 3; ++ni)
            acc[mi][ni] = (floatx4){0.f, 0.f, 0.f, 0.f};

    // prologue: tile0 {A,B} -> buf0 (5 loads); tile1 {B} -> buf1 (3 loads)
    stageA(0, 0); stageB(0, 0);
    stageB(1, 1);
    asm volatile("s_waitcnt vmcnt(3)" ::: "memory");   // tile0 landed
    asm volatile("s_barrier" ::: "memory");

    int b = 0;
#pragma unroll 1
    for (int kt = 0; kt < NT; ++kt, b ^= 1) {
        const unsigned short* lA = &lds[b * 20480];
        const unsigned short* lB = &lds[b * 20480 + 8192];

        // ---- phase 0: bfr + af(mi 0,1); stage A(t+1) -> buf^1 ----
        short8 bfr[3][2];
#pragma unroll
        for (int ni = 0; ni < 3; ++ni) {
            const int rb = wn * 48 + ni * 16 + m16;
#pragma unroll
            for (int ks = 0; ks < 2; ++ks)
                bfr[ni][ks] = *(const short8*)&lB[(rb >> 6) * 4096 + (rb & 63) * 64
                                                  + ((((ks << 2) | quad) ^ sw7) << 3)];
        }
        short8 af[2][2];
#pragma unroll
        for (int jj = 0; jj < 2; ++jj)
#pragma unroll
            for (int ks = 0; ks < 2; ++ks)
                af[jj][ks] = *(const short8*)&lA[wm * 4096 + (jj * 16 + m16) * 64
                                                 + ((((ks << 2) | quad) ^ sw7) << 3)];
        if (kt + 1 < NT) stageA(kt + 1, b ^ 1);
        asm volatile("s_barrier" ::: "memory");
        asm volatile("s_waitcnt lgkmcnt(0)" ::: "memory");
        __builtin_amdgcn_sched_barrier(0);
        __builtin_amdgcn_s_setprio(1);
#pragma unroll
        for (int ks = 0; ks < 2; ++ks)
#pragma unroll
            for (int jj = 0; jj < 2; ++jj)
#pragma unroll
                for (int ni = 0; ni < 3; ++ni)
                    acc[jj][ni] = __builtin_amdgcn_mfma_f32_16x16x32_bf16(
                        af[jj][ks], bfr[ni][ks], acc[jj][ni], 0, 0, 0);
        __builtin_amdgcn_s_setprio(0);
        asm volatile("s_barrier" ::: "memory");

        // ---- phase 1: af(mi 2,3); stage B(t+2) -> buf ----
        short8 af2[2][2];
#pragma unroll
        for (int jj = 0; jj < 2; ++jj)
#pragma unroll
            for (int ks = 0; ks < 2; ++ks)
                af2[jj][ks] = *(const short8*)&lA[wm * 4096 + ((2 + jj) * 16 + m16) * 64
                                                  + ((((ks << 2) | quad) ^ sw7) << 3)];
        if (kt + 2 < NT) stageB(kt + 2, b);
        asm volatile("s_barrier" ::: "memory");
        asm volatile("s_waitcnt lgkmcnt(0)" ::: "memory");
        __builtin_amdgcn_sched_barrier(0);
        __builtin_amdgcn_s_setprio(1);
#pragma unroll
        for (int ks = 0; ks < 2; ++ks)
#pragma unroll
            for (int jj = 0; jj < 2; ++jj)
#pragma unroll
                for (int ni = 0; ni < 3; ++ni)
                    acc[2 + jj][ni] = __builtin_amdgcn_mfma_f32_16x16x32_bf16(
                        af2[jj][ks], bfr[ni][ks], acc[2 + jj][ni], 0, 0, 0);
        __builtin_amdgcn_s_setprio(0);
        if (kt < NT - 2) { asm volatile("s_waitcnt vmcnt(3)" ::: "memory"); }
        else             { asm volatile("s_waitcnt vmcnt(0)" ::: "memory"); }
        asm volatile("s_barrier" ::: "memory");
    }

    // -------- epilogue: per-(wave,ni) Q/K vs V branch --------
#pragma unroll
    for (int ni = 0; ni < 3; ++ni) {
        const int c0 = col0 + wn * 48 + ni * 16;      // lane adds m16
        if (c0 < 2048) {
            // Q/K: bf16 rows at stride QKN
#pragma unroll
            for (int mi = 0; mi < 4; ++mi)
#pragma unroll
                for (int reg = 0; reg < 4; ++reg) {
                    const int r = row0 + wm * 64 + mi * 16 + quad * 4 + reg;
                    Cqk[(size_t)r * QKN + c0 + m16] = f2bf(acc[mi][ni][reg] + bv[ni]);
                }
        } else {
            // V: direct transposed store to VtG[bh][d][t] (8-B runs, 4 tokens)
            const int cb = c0 - 2048;
            const int hsel = cb >> 6;                 // head
            const int dd = (cb & 63) + m16;           // feature within head
            const int bq = row0 >> 10;                // batch
            const int tb = row0 & 1023;
            unsigned short* drow = VtG
                + (size_t)(bq * Hz + hsel) * (HDz * Tz)
                + (size_t)dd * Tz + tb;
#pragma unroll
            for (int mi = 0; mi < 4; ++mi) {
                const int t = wm * 64 + mi * 16 + quad * 4;
                unsigned pk[2];
                pk[0] = pkbf(acc[mi][ni][0] + bv[ni], acc[mi][ni][1] + bv[ni]);
                pk[1] = pkbf(acc[mi][ni][2] + bv[ni], acc[mi][ni][3] + bv[ni]);
                *(uint2*)&drow[t] = *(uint2*)pk;
            }
        }
    }
}

// ---------------------------------------------------------------------------
// proj GEMM template (R3-measured improvement, kept verbatim).
// 256x128 tile, intra-tile pipelined, 256 blocks = exactly 1 dispatch wave.
// ---------------------------------------------------------------------------
template<int NI, int MODE, int NXB>
__global__ __launch_bounds__(512) void gemm8p(
    const unsigned short* __restrict__ A,
    const unsigned short* __restrict__ Bt,
    const float* __restrict__ bias,
    void* __restrict__ Cout, unsigned short* __restrict__ VtG)
{
    constexpr int LDSB = 16384 + NI * 4096;   // shorts per buffer
    constexpr int NT = 16;                    // K / 64
    constexpr int NBLK = (Mz / 256) * NXB;
    constexpr int CHUNK = NBLK / 8;
    constexpr int NOUT = NXB * NI * 64;       // output row width
    __shared__ unsigned short lds[2 * LDSB];

    const int tid = threadIdx.x;
    const int lane = tid & 63;
    const int w = tid >> 6;                 // 0..7
    const int wm = w >> 2, wn = w & 3;      // 2M x 4N wave grid
    const int quad = lane >> 4, m16 = lane & 15;
    const int sw7 = m16 & 7;

    int wg = blockIdx.x;
    wg = (wg & 7) * CHUNK + (wg >> 3);
    const int bx = wg % NXB, by = wg / NXB;
    const int row0 = by * 256, col0 = bx * (NI * 64);

    const int srow = tid >> 3;                              // 0..63
    const int scol = ((tid & 7) ^ (srow & 7)) * 8;          // pre-swizzled src
    const unsigned short* sA[2][2];
    const unsigned short* sBu[NI];
#pragma unroll
    for (int h = 0; h < 2; ++h)
#pragma unroll
        for (int c = 0; c < 2; ++c)
            sA[h][c] = A + (size_t)(row0 + h * 128 + c * 64 + srow) * Cz + scol;
#pragma unroll
    for (int u = 0; u < NI; ++u)
        sBu[u] = Bt + (size_t)(col0 + u * 64 + srow) * Cz + scol;

    auto stage_tile = [&](int kt, int db) {
        unsigned short* base = &lds[db * LDSB];
#pragma unroll
        for (int u = 0; u < NI; ++u)
            gload16(sBu[u] + kt * 64, base + 16384 + u * 4096 + w * 512);
        gload16(sA[0][0] + kt * 64, base + w * 512);
        gload16(sA[0][1] + kt * 64, base + w * 512 + 4096);
        gload16(sA[1][0] + kt * 64, base + 8192 + w * 512);
        gload16(sA[1][1] + kt * 64, base + 8192 + w * 512 + 4096);
    };

    float bv[NI];
#pragma unroll
    for (int ni = 0; ni < NI; ++ni)
        bv[ni] = bias[col0 + wn * (NI * 16) + ni * 16 + m16];
    asm volatile("s_waitcnt vmcnt(0)" ::: "memory");

    floatx4 acc[8][NI];
#pragma unroll
    for (int mi = 0; mi < 8; ++mi)
#pragma unroll
        for (int ni = 0; ni < NI; ++ni)
            acc[mi][ni] = (floatx4){0.f, 0.f, 0.f, 0.f};

    stage_tile(0, 0);
    stage_tile(1, 1);

    int b = 0;
#pragma unroll 1
    for (int kt = 0; kt < NT; ++kt, b ^= 1) {
        if (kt < NT - 1) {
            if constexpr (NI == 3) asm volatile("s_waitcnt vmcnt(7)" ::: "memory");
            else                   asm volatile("s_waitcnt vmcnt(6)" ::: "memory");
        } else {
            asm volatile("s_waitcnt vmcnt(0)" ::: "memory");
        }
        asm volatile("s_barrier" ::: "memory");

        const unsigned short* lA = &lds[b * LDSB];
        const unsigned short* lB = &lds[b * LDSB + 16384];

        auto loadA = [&](auto pc, short8 (&af)[2][2]) {
            constexpr int p = decltype(pc)::value;
            constexpr int hf = p >> 1;
#pragma unroll
            for (int j = 0; j < 2; ++j) {
                const int ra = ((p & 1) * 64 + j * 32 + wm * 16 + m16) * 64;
#pragma unroll
                for (int ks = 0; ks < 2; ++ks)
                    af[j][ks] = *(const short8*)&lA[hf * 8192 + ra + ((((ks << 2) | quad) ^ sw7) << 3)];
            }
        };

        short8 bfr[NI][2];
#pragma unroll
        for (int ni = 0; ni < NI; ++ni) {
            const int rb = (wn * (NI * 16) + ni * 16 + m16) * 64;
#pragma unroll
            for (int ks = 0; ks < 2; ++ks)
                bfr[ni][ks] = *(const short8*)&lB[rb + ((((ks << 2) | quad) ^ sw7) << 3)];
        }

        auto cluster = [&](auto pc, short8 (&af)[2][2]) {
            constexpr int p = decltype(pc)::value;
            __builtin_amdgcn_s_setprio(1);
#pragma unroll
            for (int ks = 0; ks < 2; ++ks)
#pragma unroll
                for (int j = 0; j < 2; ++j)
#pragma unroll
                    for (int ni = 0; ni < NI; ++ni)
                        acc[p * 2 + j][ni] = __builtin_amdgcn_mfma_f32_16x16x32_bf16(
                            af[j][ks], bfr[ni][ks], acc[p * 2 + j][ni], 0, 0, 0);
            __builtin_amdgcn_s_setprio(0);
        };

        short8 afA[2][2], afB[2][2];
        loadA(IC<0>{}, afA);
        __builtin_amdgcn_sched_barrier(0);
        loadA(IC<1>{}, afB);
        __builtin_amdgcn_sched_barrier(0);
        asm volatile("s_waitcnt lgkmcnt(4)" ::: "memory");
        __builtin_amdgcn_sched_barrier(0);
        cluster(IC<0>{}, afA);
        loadA(IC<2>{}, afA);
        __builtin_amdgcn_sched_barrier(0);
        asm volatile("s_waitcnt lgkmcnt(4)" ::: "memory");
        __builtin_amdgcn_sched_barrier(0);
        cluster(IC<1>{}, afB);
        loadA(IC<3>{}, afB);
        __builtin_amdgcn_sched_barrier(0);
        asm volatile("s_waitcnt lgkmcnt(4)" ::: "memory");
        __builtin_amdgcn_sched_barrier(0);
        cluster(IC<2>{}, afA);
        asm volatile("s_waitcnt lgkmcnt(0)" ::: "memory");
        __builtin_amdgcn_sched_barrier(0);
        if (kt + 2 < NT) {
            asm volatile("s_barrier" ::: "memory");
            stage_tile(kt + 2, b);
        }
        __builtin_amdgcn_sched_barrier(0);
        cluster(IC<3>{}, afB);
    }

    // -------- epilogue --------
    if constexpr (MODE == 0) {
#pragma unroll
        for (int ni = 0; ni < NI; ++ni) {
            const int c = col0 + wn * (NI * 16) + ni * 16 + m16;
#pragma unroll
            for (int mi = 0; mi < 8; ++mi)
#pragma unroll
                for (int reg = 0; reg < 4; ++reg) {
                    const int r = row0 + mi * 32 + wm * 16 + quad * 4 + reg;
                    ((float*)Cout)[(size_t)r * NOUT + c] = acc[mi][ni][reg] + bv[ni];
                }
        }
    } else {
#pragma unroll
        for (int ni = 0; ni < NI; ++ni) {
            const int c0 = col0 + wn * (NI * 16) + ni * 16;
            if (c0 < 2048) {
#pragma unroll
                for (int mi = 0; mi < 8; ++mi)
#pragma unroll
                    for (int reg = 0; reg < 4; ++reg) {
                        const int r = row0 + mi * 32 + wm * 16 + quad * 4 + reg;
                        ((unsigned short*)Cout)[(size_t)r * QKN + c0 + m16] =
                            f2bf(acc[mi][ni][reg] + bv[ni]);
                    }
            } else {
                const int cb = c0 - 2048;
                const int hsel = cb >> 6;
                const int dd = (cb & 63) + m16;
                const int bq = row0 >> 10;
                const int tb = row0 & 1023;
                unsigned short* drow = VtG
                    + (size_t)(bq * Hz + hsel) * (HDz * Tz)
                    + (size_t)dd * Tz + tb;
#pragma unroll
                for (int mi = 0; mi < 8; ++mi) {
                    const int t = mi * 32 + wm * 16 + quad * 4;
                    unsigned pk[2];
                    pk[0] = pkbf(acc[mi][ni][0] + bv[ni], acc[mi][ni][1] + bv[ni]);
                    pk[1] = pkbf(acc[mi][ni][2] + bv[ni], acc[mi][ni][3] + bv[ni]);
                    *(uint2*)&drow[t] = *(uint2*)pk;
                }
            }
        }
    }
}

// ---------------------------------------------------------------------------
// MFMA causal flash attention.  R7 change: ONE q-tile per block, grid 2048
// -> ~8 blocks/CU resident (was 4) = ~4 waves/SIMD (was 2).  R5 counters:
// MfmaUtil ~10%, VALUBusy ~34% -> latency-bound at 2 waves/SIMD; LDS (32 KiB)
// allows 5 blocks/CU, grid was the limiter.  qi = 15 - (bid>>7): long tiles
// launch first (LPT) so the causal imbalance fills the tail.  bh = bid&127
// keeps XCD = bh%8 (R5-verified K/V L2 locality).  Body unchanged.
// ---------------------------------------------------------------------------
__global__ __launch_bounds__(128) void attn_kernel(const unsigned short* __restrict__ qkb,
    const unsigned short* __restrict__ VtG, unsigned short* __restrict__ attb)
{
    __shared__ unsigned short Ks[2][64 * 64];   // [key][d swizzled]
    __shared__ unsigned short Vs[2][64 * 64];   // [d][key swizzled]

    const int bid = blockIdx.x;
    const int qi = 15 - (bid >> 7);             // q-tile, big first
    const int bh = bid & 127;
    const int b = bh >> 4, h = bh & 15;
    const int tid = threadIdx.x, lane = tid & 63, w = tid >> 6;   // w in {0,1}
    const int quad = lane >> 4, m16 = lane & 15;

    const unsigned short* Kb = qkb + (size_t)(b * Tz) * QKN + Cz + h * HDz;
    const unsigned short* Vb = VtG + (size_t)bh * (HDz * Tz);

    const int l3 = lane >> 3, l7 = lane & 7;
    const int gsw = ((l7 ^ l3) << 3);           // staging source swizzle
    const int sw = m16 & 7;                     // read-side row swizzle key
    const int p0 = (quad ^ sw) << 3;            // K-frag group offset (elems)

    // ones A-frag for the l-sum MFMA: A[m=0][k]=1, else 0
    short8 onesf = (short8){0,0,0,0,0,0,0,0};
    if (m16 == 0) {
        const short one = (short)0x3F80;
        onesf = (short8){one,one,one,one,one,one,one,one};
    }

    int srow[4];
#pragma unroll
    for (int i = 0; i < 4; ++i) srow[i] = w * 32 + i * 8 + l3;

    // prologue: stage key-tile 0 into buf 0
#pragma unroll
    for (int i = 0; i < 4; ++i) {
        gload16(Kb + (size_t)srow[i] * QKN + gsw, &Ks[0][(w * 4 + i) * 512]);
        gload16(Vb + (size_t)srow[i] * Tz + gsw, &Vs[0][(w * 4 + i) * 512]);
    }

    // Q B-frags: rows qi*64 + w*32 + mi*16 + m16
    short8 qf[2][2];
    int qrow[2];
#pragma unroll
    for (int mi = 0; mi < 2; ++mi) {
        qrow[mi] = qi * 64 + w * 32 + mi * 16 + m16;
        const size_t rq = (size_t)(b * Tz + qrow[mi]) * QKN + h * HDz;
        qf[mi][0] = *(const short8*)&qkb[rq + quad * 8];
        qf[mi][1] = *(const short8*)&qkb[rq + 32 + quad * 8];
    }

    floatx4 of[2][4];   // O^T accum: [d=dc*16+quad*4+reg][q=m16]
#pragma unroll
    for (int mi = 0; mi < 2; ++mi)
#pragma unroll
        for (int dc = 0; dc < 4; ++dc) of[mi][dc] = (floatx4){0.f, 0.f, 0.f, 0.f};
    floatx4 lsum[2];
    lsum[0] = (floatx4){0.f, 0.f, 0.f, 0.f};
    lsum[1] = (floatx4){0.f, 0.f, 0.f, 0.f};

    int buf = 0;

    auto tile_body = [&](auto diag_c) {
        constexpr bool DIAG = decltype(diag_c)::value;
        short8 pf[2][2];
#pragma unroll
        for (int m0 = 0; m0 < 4; ++m0) {
            if (DIAG && w == 0 && m0 >= 2) continue;
            const unsigned short* kr = &Ks[buf][(m0 * 16 + m16) * 64];
            short8 kf0 = *(const short8*)&kr[p0];
            short8 kf1 = *(const short8*)&kr[p0 ^ 32];
#pragma unroll
            for (int mi = 0; mi < 2; ++mi) {
                floatx4 st = (floatx4){0.f, 0.f, 0.f, 0.f};
                st = __builtin_amdgcn_mfma_f32_16x16x32_bf16(kf0, qf[mi][0], st, 0, 0, 0);
                st = __builtin_amdgcn_mfma_f32_16x16x32_bf16(kf1, qf[mi][1], st, 0, 0, 0);
                float p[4];
#pragma unroll
                for (int reg = 0; reg < 4; ++reg) {
                    p[reg] = exp2f(st[reg] * 0.18033688f);
                    if (DIAG) {
                        int key = m0 * 16 + quad * 4 + reg;
                        int qr  = w * 32 + mi * 16 + m16;
                        p[reg] = (key <= qr) ? p[reg] : 0.f;
                    }
                }
                unsigned* pp = (unsigned*)&pf[mi][m0 >> 1];
                pp[(m0 & 1) * 2 + 0] = pkbf(p[0], p[1]);
                pp[(m0 & 1) * 2 + 1] = pkbf(p[2], p[3]);
            }
        }
#pragma unroll
        for (int kg = 0; kg < 2; ++kg) {
            if (DIAG && w == 0 && kg == 1) continue;
#pragma unroll
            for (int mi = 0; mi < 2; ++mi)
                lsum[mi] = __builtin_amdgcn_mfma_f32_16x16x32_bf16(onesf, pf[mi][kg], lsum[mi], 0, 0, 0);
#pragma unroll
            for (int dc = 0; dc < 4; ++dc) {
                const unsigned short* vrow = &Vs[buf][(dc * 16 + m16) * 64];
                const int g0 = kg * 4 + (quad >> 1);
                const int off = (quad & 1) * 4;
                short4v v0 = *(const short4v*)&vrow[((g0 ^ sw) << 3) + off];
                short4v v1 = *(const short4v*)&vrow[(((g0 + 2) ^ sw) << 3) + off];
                short8 vf;
                vf[0] = v0[0]; vf[1] = v0[1]; vf[2] = v0[2]; vf[3] = v0[3];
                vf[4] = v1[0]; vf[5] = v1[1]; vf[6] = v1[2]; vf[7] = v1[3];
#pragma unroll
                for (int mi = 0; mi < 2; ++mi)
                    of[mi][dc] = __builtin_amdgcn_mfma_f32_16x16x32_bf16(vf, pf[mi][kg], of[mi][dc], 0, 0, 0);
            }
        }
    };

    for (int ki = 0; ki <= qi; ++ki) {
        __syncthreads();
        if (ki < qi) {
            const size_t ko = (size_t)(ki + 1) * 64;
#pragma unroll
            for (int i = 0; i < 4; ++i) {
                gload16(Kb + (ko + srow[i]) * QKN + gsw, &Ks[buf ^ 1][(w * 4 + i) * 512]);
                gload16(Vb + (size_t)srow[i] * Tz + ko + gsw, &Vs[buf ^ 1][(w * 4 + i) * 512]);
            }
        }
        if (ki == qi) tile_body(std::true_type{});
        else          tile_body(std::false_type{});
        buf ^= 1;
    }

#pragma unroll
    for (int mi = 0; mi < 2; ++mi) {
        const float l = __shfl(lsum[mi][0], m16);   // from lanes 0..15
        const float inv = 1.f / l;
        const size_t orow = (size_t)(b * Tz + qrow[mi]) * Cz + h * HDz;
#pragma unroll
        for (int dc = 0; dc < 4; ++dc) {
            ushort4 o;
            o.x = f2bf(of[mi][dc][0] * inv);
            o.y = f2bf(of[mi][dc][1] * inv);
            o.z = f2bf(of[mi][dc][2] * inv);
            o.w = f2bf(of[mi][dc][3] * inv);
            *(ushort4*)&attb[orow + dc * 16 + quad * 4] = o;
        }
    }
}

// ---------------------------------------------------------------------------
extern "C" void kernel_launch(void* const* d_in, const int* in_sizes, int n_in,
                              void* d_out, int out_size, void* d_ws, size_t ws_size,
                              hipStream_t stream)
{
    const float* x     = (const float*)d_in[0];
    const float* Wqkv  = (const float*)d_in[1];
    const float* bqkv  = (const float*)d_in[2];
    const float* Wproj = (const float*)d_in[3];
    const float* bproj = (const float*)d_in[4];
    float* out = (float*)d_out;

    // Workspace (76 MB): attb aliases xb (xb fully consumed by gemm1 before
    // attn writes attb; stream-ordered, re-poison-safe).
    unsigned short* xb     = (unsigned short*)d_ws;              // 16 MB
    unsigned short* Wqkvt  = xb + (size_t)Mz * Cz;               //  6 MB
    unsigned short* Wprojt = Wqkvt + (size_t)N1 * Cz;            //  2 MB
    unsigned short* qkb    = Wprojt + (size_t)Cz * Cz;           // 32 MB
    unsigned short* VtG    = qkb + (size_t)Mz * QKN;             // 16 MB
    unsigned short* attb   = xb;                                 // alias

    prep_kernel<<<12288, 256, 0, stream>>>(x, xb, Wqkv, Wqkvt, Wproj, Wprojt);

    // QKV GEMM: 128x192 tile, 80 KiB LDS -> 2 blocks/CU, 1024 blocks (R5)
    gemm128_qkv<<<1024, 512, 0, stream>>>(xb, Wqkvt, bqkv, qkb, VtG);

    // attn: 2048 blocks, 1 q-tile each (LPT order), bh in low bits for XCD/L2
    attn_kernel<<<2048, 128, 0, stream>>>(qkb, VtG, attb);

    gemm8p<2, 0, 8><<<256, 512, 0, stream>>>(attb, Wprojt, bproj, out, nullptr);
}